// Round 1
// baseline (355.118 us; speedup 1.0000x reference)
//
#include <hip/hip_runtime.h>

// CoOccurrence: per-pixel 5x5 neighborhood cosine-similarity weighting.
// x: (8, 64, 112, 112) f32, spatial_weight: (25,) f32 -> out: (8, 64, 112, 112) f32.

constexpr int Bc = 8, Cc = 64, Hc = 112, Wc = 112;
constexpr int HWc = Hc * Wc;
constexpr int Kc = 5, PADc = 2, K2c = 25;
constexpr float EPSc = 1e-8f;

__global__ __launch_bounds__(64) void cooc_kernel(
    const float* __restrict__ x, const float* __restrict__ swg,
    float* __restrict__ out)
{
    const int p = blockIdx.x * 64 + threadIdx.x;  // pixel id over B*H*W (exact grid)
    const int b = p / HWc;
    const int hw = p - b * HWc;
    const int h = hw / Wc;
    const int w = hw - h * Wc;
    const float* xb = x + (size_t)b * Cc * HWc + hw;   // channel-0 at this pixel
    float* ob = out + (size_t)b * Cc * HWc + hw;

    // Tap offsets; OOB taps clamped to offset 0 (in-bounds load, weight forced
    // to 0 later — zero-padded taps contribute exactly 0 to the output).
    int off[K2c];
    bool valid[K2c];
#pragma unroll
    for (int ki = 0; ki < Kc; ++ki) {
#pragma unroll
        for (int kj = 0; kj < Kc; ++kj) {
            const int k = ki * Kc + kj;
            const int dh = ki - PADc, dw = kj - PADc;
            const bool v = ((unsigned)(h + dh) < (unsigned)Hc) &&
                           ((unsigned)(w + dw) < (unsigned)Wc);
            valid[k] = v;
            off[k] = v ? (dh * Wc + dw) : 0;
        }
    }

    // Phase 1: channel-outer accumulation of dot(center, tap) and ||tap||^2.
    float dot[K2c], nq2[K2c];
#pragma unroll
    for (int k = 0; k < K2c; ++k) { dot[k] = 0.f; nq2[k] = 0.f; }
    float nx2 = 0.f;

#pragma unroll 4
    for (int c = 0; c < Cc; ++c) {
        const float* xc = xb + c * HWc;
        const float xv = *xc;
        nx2 = fmaf(xv, xv, nx2);
#pragma unroll
        for (int k = 0; k < K2c; ++k) {
            const float xq = xc[off[k]];
            dot[k] = fmaf(xv, xq, dot[k]);
            nq2[k] = fmaf(xq, xq, nq2[k]);
        }
    }

    // Weights: sim = dot / max(||x_p||*||x_q||, eps); w = (sim+1)/2 * sw[k].
    const float nx = sqrtf(nx2);
    float wk[K2c];
#pragma unroll
    for (int k = 0; k < K2c; ++k) {
        const float denom = fmaxf(nx * sqrtf(nq2[k]), EPSc);
        const float sim = dot[k] / denom;
        wk[k] = valid[k] ? ((sim + 1.f) * 0.5f) * swg[k] : 0.f;
    }

    // Phase 2: out[c] = sum_k w_k * x[c, q_k]  (reloads hit L1/L2).
#pragma unroll 4
    for (int c = 0; c < Cc; ++c) {
        const float* xc = xb + c * HWc;
        float acc = 0.f;
#pragma unroll
        for (int k = 0; k < K2c; ++k) {
            acc = fmaf(wk[k], xc[off[k]], acc);
        }
        ob[c * HWc] = acc;
    }
}

extern "C" void kernel_launch(void* const* d_in, const int* in_sizes, int n_in,
                              void* d_out, int out_size, void* d_ws, size_t ws_size,
                              hipStream_t stream) {
    const float* x = (const float*)d_in[0];
    const float* sw = (const float*)d_in[1];
    float* out = (float*)d_out;
    const int npix = Bc * HWc;                 // 100352 = 1568 * 64 exactly
    cooc_kernel<<<dim3(npix / 64), dim3(64), 0, stream>>>(x, sw, out);
}

// Round 2
// 206.265 us; speedup vs baseline: 1.7217x; 1.7217x over previous
//
#include <hip/hip_runtime.h>

// CoOccurrence: per-pixel 5x5 neighborhood cosine-similarity weighting.
// x: (8, 64, 112, 112) f32, spatial_weight: (25,) f32 -> out: (8, 64, 112, 112) f32.
//
// R2 structure:
//   kernel 1: n2[p] = sum_c x[c,p]^2  (to d_ws; ||patch_k|| == ||x|| shifted)
//   kernel 2: lane = (pixel%16, channel-quarter); dot[25] over 16 channels,
//             shfl_xor(16/32) reduce, weights, then per-quarter output pass.

constexpr int Bc = 8, Cc = 64, Hc = 112, Wc = 112;
constexpr int HWc = Hc * Wc;
constexpr int Kc = 5, PADc = 2, K2c = 25;
constexpr float EPSc = 1e-8f;
constexpr int NPIX = Bc * HWc;  // 100352 = 392*256 = 6272*16

__global__ __launch_bounds__(256) void norm2_kernel(
    const float* __restrict__ x, float* __restrict__ n2)
{
    const int p = blockIdx.x * 256 + threadIdx.x;   // exact grid
    const int b = p / HWc;
    const int hw = p - b * HWc;
    const float* xb = x + (size_t)b * Cc * HWc + hw;
    float s = 0.f;
#pragma unroll 8
    for (int c = 0; c < Cc; ++c) {
        const float v = xb[c * HWc];
        s = fmaf(v, v, s);
    }
    n2[p] = s;
}

template <bool USE_N2>
__global__ __launch_bounds__(256) void cooc_kernel(
    const float* __restrict__ x, const float* __restrict__ swg,
    const float* __restrict__ n2, float* __restrict__ out)
{
    const int t = blockIdx.x * 256 + threadIdx.x;
    const int lane = threadIdx.x & 63;
    const int g = lane & 15;        // pixel-in-wave
    const int q = lane >> 4;        // channel quarter
    const int p = (t >> 6) * 16 + g;  // pixel id, exact coverage
    const int b = p / HWc;
    const int hw = p - b * HWc;
    const int h = hw / Wc;
    const int w = hw - h * Wc;
    const float* xb = x + (size_t)b * Cc * HWc + hw;   // channel-0 at this pixel
    float* ob = out + (size_t)b * Cc * HWc + hw;

    // Tap offsets; OOB taps clamped to 0 (in-bounds load, weight forced to 0;
    // zero-padded taps contribute exactly 0 to the reference output).
    int off[K2c];
    bool valid[K2c];
#pragma unroll
    for (int ki = 0; ki < Kc; ++ki) {
#pragma unroll
        for (int kj = 0; kj < Kc; ++kj) {
            const int k = ki * Kc + kj;
            const int dh = ki - PADc, dw = kj - PADc;
            const bool v = ((unsigned)(h + dh) < (unsigned)Hc) &&
                           ((unsigned)(w + dw) < (unsigned)Wc);
            valid[k] = v;
            off[k] = v ? (dh * Wc + dw) : 0;
        }
    }

    // Phase 1: dot(center, tap) over this lane's 16 channels.
    float dot[K2c];
#pragma unroll
    for (int k = 0; k < K2c; ++k) dot[k] = 0.f;
    float nq2[K2c];
    if (!USE_N2) {
#pragma unroll
        for (int k = 0; k < K2c; ++k) nq2[k] = 0.f;
    }

    const float* xq = xb + (size_t)(q * 16) * HWc;
#pragma unroll 4
    for (int cc = 0; cc < 16; ++cc) {
        const float* xc = xq + cc * HWc;
        const float xv = *xc;
#pragma unroll
        for (int k = 0; k < K2c; ++k) {
            const float xv2 = xc[off[k]];
            dot[k] = fmaf(xv, xv2, dot[k]);
            if (!USE_N2) nq2[k] = fmaf(xv2, xv2, nq2[k]);
        }
    }

    // Reduce across the 4 channel-quarters (lanes l, l^16, l^32, l^48).
#pragma unroll
    for (int k = 0; k < K2c; ++k) {
        dot[k] += __shfl_xor(dot[k], 16);
        dot[k] += __shfl_xor(dot[k], 32);
        if (!USE_N2) {
            nq2[k] += __shfl_xor(nq2[k], 16);
            nq2[k] += __shfl_xor(nq2[k], 32);
        }
    }

    // Weights: sim = dot / max(||x_p||*||x_q||, eps); w = (sim+1)/2 * sw[k].
    float nx2;
    if (USE_N2) nx2 = n2[p];
    else        nx2 = nq2[12];         // center tap
    const float nx = sqrtf(nx2);
    float wk[K2c];
#pragma unroll
    for (int k = 0; k < K2c; ++k) {
        const float q2 = USE_N2 ? n2[p + off[k]] : nq2[k];
        const float denom = fmaxf(nx * sqrtf(q2), EPSc);
        const float sim = dot[k] / denom;
        wk[k] = valid[k] ? ((sim + 1.f) * 0.5f) * swg[k] : 0.f;
    }

    // Phase 2: out[c] = sum_k w_k * x[c, q_k] for this lane's 16 channels.
#pragma unroll 4
    for (int cc = 0; cc < 16; ++cc) {
        const float* xc = xq + cc * HWc;
        float acc = 0.f;
#pragma unroll
        for (int k = 0; k < K2c; ++k) {
            acc = fmaf(wk[k], xc[off[k]], acc);
        }
        ob[(size_t)(q * 16 + cc) * HWc] = acc;
    }
}

extern "C" void kernel_launch(void* const* d_in, const int* in_sizes, int n_in,
                              void* d_out, int out_size, void* d_ws, size_t ws_size,
                              hipStream_t stream) {
    const float* x = (const float*)d_in[0];
    const float* sw = (const float*)d_in[1];
    float* out = (float*)d_out;
    float* n2 = (float*)d_ws;

    const bool use_n2 = (ws_size >= (size_t)NPIX * sizeof(float));
    if (use_n2) {
        norm2_kernel<<<dim3(NPIX / 256), dim3(256), 0, stream>>>(x, n2);
        cooc_kernel<true><<<dim3(NPIX * 4 / 256), dim3(256), 0, stream>>>(x, sw, n2, out);
    } else {
        cooc_kernel<false><<<dim3(NPIX * 4 / 256), dim3(256), 0, stream>>>(x, sw, n2, out);
    }
}

// Round 3
// 96.661 us; speedup vs baseline: 3.6739x; 2.1339x over previous
//
#include <hip/hip_runtime.h>

// CoOccurrence: per-pixel 5x5 neighborhood cosine-similarity weighting.
// x: (8, 64, 112, 112) f32, spatial_weight: (25,) f32 -> out: (8, 64, 112, 112) f32.
//
// R3: LDS-staged 8x8 pixel tile (12x12 halo) per 64-thread block, channels in
// 2 chunks of 32. Phase 1 (dots + halo n2) and phase 2 (weighted gather) both
// read LDS with immediate-offset ds_read_b32. Zero-padded halo => OOB taps
// contribute exactly 0 (matches reference's zero-pad semantics), no masks.

constexpr int Cc = 64, Hc = 112, Wc = 112;
constexpr int HWc = Hc * Wc;
constexpr float EPSc = 1e-8f;
constexpr int TH = 8, TW = 8;          // pixel tile per block
constexpr int WR = 12, HALO = 144;     // 12x12 halo (pad 2 each side)
constexpr int CHUNK = 32, NCHUNK = 2;  // channel chunking
constexpr int NTX = 14;                // 112/8 tiles per row/col

__global__ __launch_bounds__(64) void cooc_kernel(
    const float* __restrict__ x, const float* __restrict__ swg,
    float* __restrict__ out)
{
    __shared__ float tile[CHUNK * HALO];   // [c][r*12+w], 18.4 KB
    __shared__ float n2s[HALO];            // per-halo-pixel sum_c x^2

    const int t = threadIdx.x;
    const int b = blockIdx.y;
    const int th = blockIdx.x / NTX, twi = blockIdx.x - th * NTX;
    const int h0 = th * TH, w0 = twi * TW;
    const int rr = t >> 3, cw = t & 7;         // thread's pixel in tile
    const int hp = (rr + 2) * WR + (cw + 2);   // center slot in halo coords

    // This thread's 2-3 staging slots among the 144 halo positions.
    const int pos0 = t, pos1 = t + 64;
    const int pos2 = (t < 16) ? t + 128 : t;   // dup of pos0 for t>=16 (benign)

    bool i0, i1, i2;
    int go0, go1, go2;
    {
        auto mk = [&](int pos, bool& inb) {
            const int r_ = pos / WR, c_ = pos - r_ * WR;
            const int gh = h0 + r_ - 2, gw = w0 + c_ - 2;
            inb = ((unsigned)gh < (unsigned)Hc) && ((unsigned)gw < (unsigned)Wc);
            return gh * Wc + gw;
        };
        go0 = mk(pos0, i0); go1 = mk(pos1, i1); go2 = mk(pos2, i2);
    }
    const float* xb = x + (size_t)b * Cc * HWc;

    auto stage = [&](int c0) {
        const float* g = xb + (size_t)c0 * HWc;
#pragma unroll 8
        for (int c = 0; c < CHUNK; ++c) {
            const float* gc = g + (size_t)c * HWc;
            const float v0 = i0 ? gc[go0] : 0.f;
            const float v1 = i1 ? gc[go1] : 0.f;
            const float v2 = i2 ? gc[go2] : 0.f;
            tile[c * HALO + pos0] = v0;
            tile[c * HALO + pos1] = v1;
            tile[c * HALO + pos2] = v2;
        }
    };

    float dot[25];
#pragma unroll
    for (int k = 0; k < 25; ++k) dot[k] = 0.f;
    float a0 = 0.f, a1 = 0.f, a2 = 0.f;   // halo n2 partials

    const float* tb = &tile[hp - 26];     // taps at immediate offsets 0..52

    // ---- sweep 1: dots + halo n2 ----
    for (int ch = 0; ch < NCHUNK; ++ch) {
        __syncthreads();
        stage(ch * CHUNK);
        __syncthreads();
#pragma unroll 4
        for (int c = 0; c < CHUNK; ++c) {
            const float* p = tb + c * HALO;
            const float xv = p[26];
#pragma unroll
            for (int k = 0; k < 25; ++k) {
                const int off = (k / 5) * WR + (k % 5);
                dot[k] = fmaf(xv, p[off], dot[k]);
            }
        }
#pragma unroll 4
        for (int c = 0; c < CHUNK; ++c) {
            const float* q = &tile[c * HALO];
            const float u0 = q[pos0], u1 = q[pos1], u2 = q[pos2];
            a0 = fmaf(u0, u0, a0);
            a1 = fmaf(u1, u1, a1);
            a2 = fmaf(u2, u2, a2);
        }
    }

    __syncthreads();                  // tile reads done; publish n2
    n2s[pos0] = a0;
    n2s[pos1] = a1;
    if (t < 16) n2s[pos2] = a2;
    __syncthreads();

    // ---- weights (wk overwrites dot) ----
    const float nx = sqrtf(n2s[hp]);
#pragma unroll
    for (int k = 0; k < 25; ++k) {
        const int off = (k / 5) * WR + (k % 5);
        const float nq = sqrtf(n2s[hp - 26 + off]);
        const float denom = fmaxf(nx * nq, EPSc);
        const float sim = dot[k] / denom;
        dot[k] = (sim + 1.f) * 0.5f * swg[k];
    }

    // ---- sweep 2: out[c] = sum_k wk * tap ----
    float* ob = out + (size_t)b * Cc * HWc + (h0 + rr) * Wc + (w0 + cw);
    for (int ch = 0; ch < NCHUNK; ++ch) {
        __syncthreads();
        stage(ch * CHUNK);
        __syncthreads();
#pragma unroll 4
        for (int c = 0; c < CHUNK; ++c) {
            const float* p = tb + c * HALO;
            float acc = 0.f;
#pragma unroll
            for (int k = 0; k < 25; ++k) {
                const int off = (k / 5) * WR + (k % 5);
                acc = fmaf(dot[k], p[off], acc);
            }
            ob[(size_t)(ch * CHUNK + c) * HWc] = acc;
        }
    }
}

extern "C" void kernel_launch(void* const* d_in, const int* in_sizes, int n_in,
                              void* d_out, int out_size, void* d_ws, size_t ws_size,
                              hipStream_t stream) {
    const float* x = (const float*)d_in[0];
    const float* sw = (const float*)d_in[1];
    float* out = (float*)d_out;
    cooc_kernel<<<dim3(NTX * NTX, 8), dim3(64), 0, stream>>>(x, sw, out);
}